// Round 4
// baseline (67.483 us; speedup 1.0000x reference)
//
#include <hip/hip_runtime.h>
#include <math.h>

// BettingLoss: scalar loss over B=1048576 races, T=8 dogs.
// Inputs (float32, each B*T): predicted_probs, true_winners(one-hot),
// market_odds, gumbel_noise. Output: 1 float32 scalar.
//
// R3: back to R0's per-thread-race structure (best replay time so far).
// Adds: (a) explicit 2-bank software pipeline (prefetch next race's 8
// float4 while computing current) under __launch_bounds__(256,2) so the
// compiler has VGPR headroom to keep 8 loads in flight — R0-R2 all
// collapsed to VGPR<=36 and serialized on L3 latency (~3.2 TB/s at every
// occupancy). (b) fused finalize via last-block atomic ticket — removes
// the second kernel launch from the timed graph.

constexpr int NT = 256;

__device__ __forceinline__ float fastrcp(float x) {
  return __builtin_amdgcn_rcpf(x);
}

struct Race {
  float4 a0, a1, w0, w1, o0, o1, g0, g1;
};

__device__ __forceinline__ void load_race(const float4* __restrict__ pp,
                                          const float4* __restrict__ tw,
                                          const float4* __restrict__ mo,
                                          const float4* __restrict__ gn,
                                          int r, Race& R) {
  R.a0 = pp[2 * r]; R.a1 = pp[2 * r + 1];
  R.w0 = tw[2 * r]; R.w1 = tw[2 * r + 1];
  R.o0 = mo[2 * r]; R.o1 = mo[2 * r + 1];
  R.g0 = gn[2 * r]; R.g1 = gn[2 * r + 1];
}

// acc: 0=cnt, 1=sum(ce*valid), 2=sum(ce), 3=sum(soft_ep*valid),
//      4=sum(max_prob), 5=sum(entropy).  wg = race weight (0 or 1).
__device__ __forceinline__ void compute_race(const Race& R, float wg,
                                             float acc[6]) {
  float p[8] = {R.a0.x, R.a0.y, R.a0.z, R.a0.w, R.a1.x, R.a1.y, R.a1.z, R.a1.w};
  float w[8] = {R.w0.x, R.w0.y, R.w0.z, R.w0.w, R.w1.x, R.w1.y, R.w1.z, R.w1.w};
  float o[8] = {R.o0.x, R.o0.y, R.o0.z, R.o0.w, R.o1.x, R.o1.y, R.o1.z, R.o1.w};
  float g[8] = {R.g0.x, R.g0.y, R.g0.z, R.g0.w, R.g1.x, R.g1.y, R.g1.z, R.g1.w};

  // validity
  bool anypos = false;
  float simp = 0.f;
#pragma unroll
  for (int t = 0; t < 8; ++t) {
    anypos = anypos || (o[t] > 0.f);
    simp += fastrcp(fmaxf(o[t], 1.01f));
  }
  float vfw = (anypos && simp >= 0.95f) ? wg : 0.f;

  // expected profit, unmasked (soft_ep is multiplied by vfw later; when the
  // race is valid the reference mask is a no-op, when invalid the term is 0)
  float ep[8];
#pragma unroll
  for (int t = 0; t < 8; ++t)
    ep[t] = (o[t] * 1.1f * p[t] - 1.f) * (0.02f * 0.95f);

  // gumbel-softmax selection: softmax(ep*100 + g*10)
  float z[8], zm = -INFINITY;
#pragma unroll
  for (int t = 0; t < 8; ++t) {
    z[t] = ep[t] * 100.f + g[t] * 10.f;
    zm = fmaxf(zm, z[t]);
  }
  float s2 = 0.f, sp = 0.f;
#pragma unroll
  for (int t = 0; t < 8; ++t) {
    float e = __expf(z[t] - zm);
    s2 += e;
    sp += e * ep[t];
  }
  float soft_ep = sp * fastrcp(s2);

  // cross-entropy (probs treated as logits), one-hot label
  float m = -INFINITY;
#pragma unroll
  for (int t = 0; t < 8; ++t) m = fmaxf(m, p[t]);
  float se = 0.f, pl = 0.f;
#pragma unroll
  for (int t = 0; t < 8; ++t) {
    se += __expf(p[t] - m);
    pl += w[t] * p[t];
  }
  float ce = m + __logf(se) - pl;

  // entropy
  float ent = 0.f;
#pragma unroll
  for (int t = 0; t < 8; ++t) ent -= p[t] * __logf(p[t] + 1e-8f);

  acc[0] += vfw;
  acc[1] += ce * vfw;
  acc[2] += ce * wg;
  acc[3] += soft_ep * vfw;
  acc[4] += m * wg;
  acc[5] += ent * wg;
}

// block-reduce 6 accumulators, publish partials, last block finalizes.
__device__ __forceinline__ void reduce_and_finish(float acc[6],
                                                  float* __restrict__ partials,
                                                  unsigned* __restrict__ counter,
                                                  float* __restrict__ out,
                                                  int nb, double Bd) {
  __shared__ float red[NT / 64][6];
#pragma unroll
  for (int k = 0; k < 6; ++k) {
#pragma unroll
    for (int off = 32; off >= 1; off >>= 1) acc[k] += __shfl_down(acc[k], off);
  }
  const int lane = threadIdx.x & 63, wave = threadIdx.x >> 6;
  if (lane == 0) {
#pragma unroll
    for (int k = 0; k < 6; ++k) red[wave][k] = acc[k];
  }
  __syncthreads();

  __shared__ int slast;
  if (threadIdx.x == 0) {
#pragma unroll
    for (int k = 0; k < 6; ++k) {
      float s = red[0][k] + red[1][k] + red[2][k] + red[3][k];
      partials[k * nb + blockIdx.x] = s;
    }
    unsigned c = __hip_atomic_fetch_add(counter, 1u, __ATOMIC_ACQ_REL,
                                        __HIP_MEMORY_SCOPE_AGENT);
    slast = (c == (unsigned)(nb - 1));
  }
  __syncthreads();
  if (!slast) return;

  // ---- last block: final reduction in double ----
  __shared__ double redd[NT / 64][6];
  double a[6] = {0, 0, 0, 0, 0, 0};
#pragma unroll
  for (int k = 0; k < 6; ++k)
    for (int i = threadIdx.x; i < nb; i += NT)
      a[k] += (double)__hip_atomic_load(&partials[k * nb + i], __ATOMIC_RELAXED,
                                        __HIP_MEMORY_SCOPE_AGENT);
#pragma unroll
  for (int k = 0; k < 6; ++k) {
#pragma unroll
    for (int off = 32; off >= 1; off >>= 1) a[k] += __shfl_down(a[k], off);
  }
  if (lane == 0) {
#pragma unroll
    for (int k = 0; k < 6; ++k) redd[wave][k] = a[k];
  }
  __syncthreads();
  if (threadIdx.x == 0) {
    double s[6];
#pragma unroll
    for (int k = 0; k < 6; ++k)
      s[k] = redd[0][k] + redd[1][k] + redd[2][k] + redd[3][k];
    double cnt = s[0], Scev = s[1], Sce = s[2], Ssoft = s[3], Smax = s[4],
           Sent = s[5];
    double pred = (cnt > 0.0) ? Scev / fmax(cnt, 1.0) : Sce / Bd;
    double conf = -(Smax / Bd) * 0.1;
    double bet = (cnt > 0.0) ? -Ssoft / Bd : conf;
    double entr = Sent / Bd;
    double lam = fmin(0.5 + cnt / 10000.0 * 0.5, 1.0);
    out[0] = (float)(pred + lam * bet - 0.01 * entr);
  }
}

// exact path: nraces == NITER * gridDim.x * NT, no bounds checks,
// 2-bank software pipeline.
template <int NITER>
__global__ __launch_bounds__(NT, 2) void betting_pipe(
    const float4* __restrict__ pp, const float4* __restrict__ tw,
    const float4* __restrict__ mo, const float4* __restrict__ gn,
    float* __restrict__ partials, unsigned* __restrict__ counter,
    float* __restrict__ out, int nraces) {
  const int tid0 = blockIdx.x * NT + threadIdx.x;
  const int ntot = gridDim.x * NT;

  float acc[6] = {0.f, 0.f, 0.f, 0.f, 0.f, 0.f};
  Race cur, nxt;
  load_race(pp, tw, mo, gn, tid0, cur);
#pragma unroll
  for (int it = 0; it < NITER; ++it) {
    if (it + 1 < NITER) load_race(pp, tw, mo, gn, tid0 + (it + 1) * ntot, nxt);
    compute_race(cur, 1.0f, acc);
    if (it + 1 < NITER) cur = nxt;
  }

  reduce_and_finish(acc, partials, counter, out, gridDim.x, (double)nraces);
}

// generic fallback: any nraces (grid-stride with weights)
__global__ __launch_bounds__(NT, 2) void betting_generic(
    const float4* __restrict__ pp, const float4* __restrict__ tw,
    const float4* __restrict__ mo, const float4* __restrict__ gn,
    float* __restrict__ partials, unsigned* __restrict__ counter,
    float* __restrict__ out, int nraces) {
  const int tid0 = blockIdx.x * NT + threadIdx.x;
  const int ntot = gridDim.x * NT;

  float acc[6] = {0.f, 0.f, 0.f, 0.f, 0.f, 0.f};
  for (int r = tid0; r < nraces; r += ntot) {
    Race R;
    load_race(pp, tw, mo, gn, r, R);
    compute_race(R, 1.0f, acc);
  }
  reduce_and_finish(acc, partials, counter, out, gridDim.x, (double)nraces);
}

extern "C" void kernel_launch(void* const* d_in, const int* in_sizes, int n_in,
                              void* d_out, int out_size, void* d_ws,
                              size_t ws_size, hipStream_t stream) {
  const float4* pp = (const float4*)d_in[0];
  const float4* tw = (const float4*)d_in[1];
  const float4* mo = (const float4*)d_in[2];
  const float4* gn = (const float4*)d_in[3];
  float* out = (float*)d_out;

  const int nraces = in_sizes[0] / 8;
  constexpr int NITER = 4;

  bool exact = (nraces % (NT * NITER) == 0) && nraces > 0;
  int grid = exact ? nraces / (NT * NITER) : 1024;
  // workspace: 6*grid floats of partials + 1 counter
  while ((size_t)((6 * grid + 1) * 4) > ws_size && grid > 64) {
    grid >>= 1;
    exact = false;
  }
  if (exact && grid != nraces / (NT * NITER)) exact = false;

  float* partials = (float*)d_ws;
  unsigned* counter = (unsigned*)(partials + 6 * grid);
  hipMemsetAsync(counter, 0, sizeof(unsigned), stream);

  if (exact) {
    betting_pipe<NITER><<<grid, NT, 0, stream>>>(pp, tw, mo, gn, partials,
                                                 counter, out, nraces);
  } else {
    betting_generic<<<grid, NT, 0, stream>>>(pp, tw, mo, gn, partials, counter,
                                             out, nraces);
  }
}